// Round 4
// baseline (342.246 us; speedup 1.0000x reference)
//
#include <hip/hip_runtime.h>

// Problem constants (from reference)
#define N_NODES 20000
#define BATCH   4
#define DIN     32
#define DOUT    64
#define MSTEPS  7            // M = MAX_STEP*S + 1
#define ROW     128          // DIN*BATCH, channels per node
#define NROW    896          // ROW*MSTEPS elements per node (all m packed), bf16
#define NROWU   448          // NROW in uints
#define PLN     656          // LDS plane stride (shorts): 16 rows * 40 + 16 pad
#define NROWS2  (2 * N_NODES)   // csr rows over both supports = 40000
#define SBLK    157             // ceil(NROWS2 / 256) scan blocks
#define RGRID   (N_NODES / 4)   // spmm blocks per stream (4 nodes/block)
#define TGRID   10000           // ceil(N*ROW / 256) transpose blocks

typedef short  short8 __attribute__((ext_vector_type(8)));
typedef float  f32x4  __attribute__((ext_vector_type(4)));

__device__ __forceinline__ unsigned short f2bf(float f) {
    unsigned u = __float_as_uint(f);
    unsigned r = u + 0x7fff + ((u >> 16) & 1);   // RNE to bf16
    return (unsigned short)(r >> 16);
}
__device__ __forceinline__ float bf_lo(unsigned p) { return __uint_as_float(p << 16); }
__device__ __forceinline__ float bf_hi(unsigned p) { return __uint_as_float(p & 0xffff0000u); }

// ---- Direct counting-sort CSR build ----------------------------------------
// B1: zero the per-(support,dst) degree counters.
__global__ void __launch_bounds__(256) zero_k(int* __restrict__ hist) {
    int i = blockIdx.x * 256 + threadIdx.x;
    if (i < NROWS2) hist[i] = 0;
}

// B2: degree histogram. One atomicAdd per edge (avg 32 collisions/counter).
__global__ void __launch_bounds__(256) hist_k(const int* __restrict__ dst,
                                              int* __restrict__ hist, int E) {
    int e = blockIdx.x * 256 + threadIdx.x;
    if (e < 2 * E) {
        int s = (e >= E) ? N_NODES : 0;
        atomicAdd(&hist[s + dst[e]], 1);
    }
}

// B3: per-block exclusive scan of pad8(deg); row_desc.x holds block-local
// exclusive offset (fixed up in fin_k), row_desc.y = padded length.
__global__ void __launch_bounds__(256) scan1_k(const int* __restrict__ hist,
                                               int2* __restrict__ row_desc,
                                               int* __restrict__ bsum) {
    __shared__ int sc[256];
    int t = threadIdx.x;
    int i = blockIdx.x * 256 + t;
    int deg = (i < NROWS2) ? hist[i] : 0;
    int pl = (deg + 7) & ~7;
    sc[t] = pl;
    __syncthreads();
    for (int off = 1; off < 256; off <<= 1) {
        int a = (t >= off) ? sc[t - off] : 0;
        __syncthreads();
        sc[t] += a;
        __syncthreads();
    }
    if (i < NROWS2) row_desc[i] = make_int2(sc[t] - pl, pl);
    if (t == 255) bsum[blockIdx.x] = sc[t];
}

// B4: finalize rows. Each block redundantly reduces its prefix of block sums
// (157 ints — cheaper than a separate scan dispatch), then writes final
// row_desc{start,pl}, seeds cursor=start, zero-fills the <=7 pad entries.
__global__ void __launch_bounds__(256) fin_k(int2* __restrict__ row_desc,
                                             const int* __restrict__ bsum,
                                             const int* __restrict__ hist,
                                             int* __restrict__ cursor,
                                             unsigned* __restrict__ csr) {
    __shared__ int red[256];
    int t = threadIdx.x;
    int blk = blockIdx.x;
    red[t] = (t < blk) ? bsum[t] : 0;
    __syncthreads();
    for (int off = 128; off > 0; off >>= 1) {
        if (t < off) red[t] += red[t + off];
        __syncthreads();
    }
    int boff = red[0];
    int i = blk * 256 + t;
    if (i >= NROWS2) return;
    int2 rdv = row_desc[i];
    int start = rdv.x + boff;
    int deg = hist[i];
    row_desc[i] = make_int2(start, rdv.y);
    cursor[i] = start;
    for (int j = deg; j < rdv.y; ++j) csr[start + j] = 0u;   // pad: src=0,val=0
}

// B5: scatter edges into csr rows (packed src|bf16val<<16) — fused with the
// input transpose via disjoint block ranges (blocks >= sgrid do transpose).
__global__ void __launch_bounds__(256) scat_k(const int* __restrict__ src,
                                              const int* __restrict__ dst,
                                              const float* __restrict__ vals,
                                              int* __restrict__ cursor,
                                              unsigned* __restrict__ csr,
                                              const float* __restrict__ in,
                                              unsigned short* __restrict__ xs,
                                              int E, int sgrid) {
    int t = threadIdx.x;
    if (blockIdx.x >= sgrid) {
        // transpose branch: xs[n*896 + d*4 + b] = bf16(in[b,n,d]) (slice m=0)
        int tid = (blockIdx.x - sgrid) * 256 + t;
        if (tid < N_NODES * ROW) {
            int b = tid & 3;
            int d = (tid >> 2) & 31;
            int n = tid >> 7;
            xs[(size_t)n * NROW + d * 4 + b] = f2bf(in[(b * N_NODES + n) * DIN + d]);
        }
        return;
    }
    int e = blockIdx.x * 256 + t;
    if (e < 2 * E) {
        int s = (e >= E) ? N_NODES : 0;
        int pos = atomicAdd(&cursor[s + dst[e]], 1);
        csr[pos] = (unsigned)src[e] | ((unsigned)f2bf(vals[e]) << 16);
    }
}

// ---- SpMM gather core (R1-verified): rows are multiples of 8, no tail ----
__device__ __forceinline__ void spmm_core(const int2* __restrict__ rdesc,
                                          const unsigned* __restrict__ csr,
                                          const unsigned* __restrict__ xb,
                                          const unsigned* __restrict__ xprevb,
                                          unsigned* __restrict__ yb,
                                          float alpha, int node, int lane) {
    int2 rd = rdesc[node];
    int start = rd.x, end = rd.x + rd.y;
    float l0 = 0.f, h0 = 0.f, l1 = 0.f, h1 = 0.f;
    float l2 = 0.f, h2 = 0.f, l3 = 0.f, h3 = 0.f;
    for (int e = start; e < end; e += 8) {
        unsigned c0 = csr[e],     c1 = csr[e + 1], c2 = csr[e + 2], c3 = csr[e + 3];
        unsigned c4 = csr[e + 4], c5 = csr[e + 5], c6 = csr[e + 6], c7 = csr[e + 7];
        unsigned p0 = xb[(size_t)(c0 & 0xffffu) * NROWU + lane];
        unsigned p1 = xb[(size_t)(c1 & 0xffffu) * NROWU + lane];
        unsigned p2 = xb[(size_t)(c2 & 0xffffu) * NROWU + lane];
        unsigned p3 = xb[(size_t)(c3 & 0xffffu) * NROWU + lane];
        unsigned p4 = xb[(size_t)(c4 & 0xffffu) * NROWU + lane];
        unsigned p5 = xb[(size_t)(c5 & 0xffffu) * NROWU + lane];
        unsigned p6 = xb[(size_t)(c6 & 0xffffu) * NROWU + lane];
        unsigned p7 = xb[(size_t)(c7 & 0xffffu) * NROWU + lane];
        float v0 = bf_hi(c0), v1 = bf_hi(c1), v2 = bf_hi(c2), v3 = bf_hi(c3);
        float v4 = bf_hi(c4), v5 = bf_hi(c5), v6 = bf_hi(c6), v7 = bf_hi(c7);
        l0 = fmaf(v0, bf_lo(p0), l0);  h0 = fmaf(v0, bf_hi(p0), h0);
        l1 = fmaf(v1, bf_lo(p1), l1);  h1 = fmaf(v1, bf_hi(p1), h1);
        l2 = fmaf(v2, bf_lo(p2), l2);  h2 = fmaf(v2, bf_hi(p2), h2);
        l3 = fmaf(v3, bf_lo(p3), l3);  h3 = fmaf(v3, bf_hi(p3), h3);
        l0 = fmaf(v4, bf_lo(p4), l0);  h0 = fmaf(v4, bf_hi(p4), h0);
        l1 = fmaf(v5, bf_lo(p5), l1);  h1 = fmaf(v5, bf_hi(p5), h1);
        l2 = fmaf(v6, bf_lo(p6), l2);  h2 = fmaf(v6, bf_hi(p6), h2);
        l3 = fmaf(v7, bf_lo(p7), l3);  h3 = fmaf(v7, bf_hi(p7), h3);
    }
    float r0 = alpha * ((l0 + l1) + (l2 + l3));
    float r1 = alpha * ((h0 + h1) + (h2 + h3));
    if (xprevb) {
        unsigned pp = xprevb[(size_t)node * NROWU + lane];
        r0 -= bf_lo(pp);
        r1 -= bf_hi(pp);
    }
    yb[(size_t)node * NROWU + lane] = (unsigned)f2bf(r0) | ((unsigned)f2bf(r1) << 16);
}

__global__ void __launch_bounds__(256) spmm_row_k(const int2* __restrict__ rdesc,
                                                  const unsigned* __restrict__ csr,
                                                  const unsigned short* __restrict__ x,
                                                  const unsigned short* __restrict__ xprev,
                                                  unsigned short* __restrict__ y, float alpha) {
    int node = __builtin_amdgcn_readfirstlane(blockIdx.x * 4 + (threadIdx.x >> 6));
    int lane = threadIdx.x & 63;
    spmm_core(rdesc, csr, (const unsigned*)x, (const unsigned*)xprev, (unsigned*)y,
              alpha, node, lane);
}

// dual dispatch: blocks [0,RGRID) A-stream, [RGRID,2*RGRID) B-stream, same input x.
// x3 = 2*A0*x2 - x1 ; x4 = A1*x2.
__global__ void __launch_bounds__(256) spmm_dual_k(const int2* __restrict__ rdA,
                                                   const int2* __restrict__ rdB,
                                                   const unsigned* __restrict__ csr,
                                                   const unsigned short* __restrict__ x,
                                                   const unsigned short* __restrict__ xprevA,
                                                   unsigned short* __restrict__ yA,
                                                   unsigned short* __restrict__ yB) {
    int bid = blockIdx.x;
    int second = (bid >= RGRID) ? 1 : 0;
    int node = __builtin_amdgcn_readfirstlane((bid - second * RGRID) * 4 + (threadIdx.x >> 6));
    int lane = threadIdx.x & 63;
    const int2* rd = second ? rdB : rdA;
    const unsigned* xprevb = second ? nullptr : (const unsigned*)xprevA;
    unsigned* yb = second ? (unsigned*)yB : (unsigned*)yA;
    float alpha = second ? 1.0f : 2.0f;
    spmm_core(rd, csr, (const unsigned*)x, xprevb, yb, alpha, node, lane);
}

// ---- MFMA epilogue (unchanged — verified correct) ----
__global__ void __launch_bounds__(256) epilogue_mfma_k(const unsigned short* __restrict__ xs,
                                                       const float* __restrict__ W,
                                                       const float* __restrict__ bias,
                                                       float* __restrict__ out) {
    __shared__ unsigned short Alds[28 * PLN];   // 36736 B
    int tid = threadIdx.x;
    int lane = tid & 63, ot = tid >> 6;
    int col = lane & 15, quad = lane >> 4;
    int o = ot * 16 + col;

    short8 bfrag[MSTEPS];
#pragma unroll
    for (int m = 0; m < MSTEPS; ++m) {
        short8 bf;
#pragma unroll
        for (int j = 0; j < 8; ++j)
            bf[j] = (short)f2bf(W[o * 224 + (quad * 8 + j) * 7 + m]);
        bfrag[m] = bf;
    }
    float bo = bias[o];

    int n0 = blockIdx.x * 16;
    const uint4* src = (const uint4*)(xs + (size_t)n0 * NROW);   // 1792 uint4
#pragma unroll
    for (int it = 0; it < 7; ++it) {
        int idx = tid + it * 256;
        uint4 q = src[idx];
        int r    = idx / 112;            // node row 0..15
        int off8 = idx - r * 112;        // element-octet within row
        int m    = off8 >> 4;
        int d0   = (off8 & 15) * 2;
        unsigned vals[4] = {q.x, q.y, q.z, q.w};
#pragma unroll
        for (int h = 0; h < 4; ++h) {
            int dd = d0 + (h >> 1);
            int bA = (2 * h) & 3, bB = (2 * h + 1) & 3;
            Alds[(bA * 7 + m) * PLN + r * 40 + dd] = (unsigned short)(vals[h] & 0xffffu);
            Alds[(bB * 7 + m) * PLN + r * 40 + dd] = (unsigned short)(vals[h] >> 16);
        }
    }
    __syncthreads();

    f32x4 acc[BATCH];
#pragma unroll
    for (int b = 0; b < BATCH; ++b)
        acc[b] = (f32x4){bo, bo, bo, bo};

#pragma unroll
    for (int m = 0; m < MSTEPS; ++m) {
#pragma unroll
        for (int b = 0; b < BATCH; ++b) {
            short8 a = *(const short8*)&Alds[(b * 7 + m) * PLN + col * 40 + quad * 8];
            acc[b] = __builtin_amdgcn_mfma_f32_16x16x32_bf16(a, bfrag[m], acc[b], 0, 0, 0);
        }
    }

#pragma unroll
    for (int b = 0; b < BATCH; ++b) {
#pragma unroll
        for (int reg = 0; reg < 4; ++reg) {
            int n = n0 + quad * 4 + reg;
            out[((size_t)b * N_NODES + n) * DOUT + o] = acc[b][reg];
        }
    }
}

extern "C" void kernel_launch(void* const* d_in, const int* in_sizes, int n_in,
                              void* d_out, int out_size, void* d_ws, size_t ws_size,
                              hipStream_t stream) {
    const float* inputs    = (const float*)d_in[0];
    const float* edge_vals = (const float*)d_in[1];
    const float* W         = (const float*)d_in[2];
    const float* bias      = (const float*)d_in[3];
    const int*   edge_src  = (const int*)d_in[4];
    const int*   edge_dst  = (const int*)d_in[5];
    float* out = (float*)d_out;
    const int E = in_sizes[1] / 2;   // edges per support

    // workspace layout
    unsigned short* xs = (unsigned short*)d_ws;                    // 35.84 MB
    unsigned* csr  = (unsigned*)(xs + (size_t)N_NODES * NROW);     // <= 2E + 8*NROWS2 uints
    int* hist      = (int*)(csr + ((size_t)2 * E + 8 * NROWS2));   // 40000
    int* cursor    = hist + NROWS2;                                 // 40000
    int2* row_desc = (int2*)(cursor + NROWS2);                      // 40000 int2
    int* bsum      = (int*)(row_desc + NROWS2);                     // SBLK

    const int epgrid = N_NODES / 16;
    const int egrid  = (2 * E + 255) / 256;   // edge-parallel grid (5000)

    // ---- CSR build (counting sort) + fused transpose ----
    zero_k<<<SBLK, 256, 0, stream>>>(hist);
    hist_k<<<egrid, 256, 0, stream>>>(edge_dst, hist, E);
    scan1_k<<<SBLK, 256, 0, stream>>>(hist, row_desc, bsum);
    fin_k<<<SBLK, 256, 0, stream>>>(row_desc, bsum, hist, cursor, csr);
    scat_k<<<egrid + TGRID, 256, 0, stream>>>(edge_src, edge_dst, edge_vals,
                                              cursor, csr, inputs, xs, E, egrid);

    const int2* rd0 = row_desc;
    const int2* rd1 = row_desc + N_NODES;

    // xs_m slice base = xs + m*128 (node stride NROW elements)
    unsigned short* X0 = xs + 0 * ROW;
    unsigned short* X1 = xs + 1 * ROW;
    unsigned short* X2 = xs + 2 * ROW;
    unsigned short* X3 = xs + 3 * ROW;
    unsigned short* X4 = xs + 4 * ROW;
    unsigned short* X5 = xs + 5 * ROW;
    unsigned short* X6 = xs + 6 * ROW;

    // support 0: xs1 = A0 x0 ; xs2 = 2 A0 xs1 - xs0
    spmm_row_k<<<RGRID, 256, 0, stream>>>(rd0, csr, X0, nullptr, X1, 1.0f);
    spmm_row_k<<<RGRID, 256, 0, stream>>>(rd0, csr, X1, X0,      X2, 2.0f);
    // xs3 = 2 A0 xs2 - xs1  ||  xs4 = A1 xs2   (independent; merged dispatch)
    spmm_dual_k<<<2 * RGRID, 256, 0, stream>>>(rd0, rd1, csr, X2, X1, X3, X4);
    // support 1 tail: xs5 = 2 A1 xs4 - xs2 ; xs6 = 2 A1 xs5 - xs4
    spmm_row_k<<<RGRID, 256, 0, stream>>>(rd1, csr, X4, X2, X5, 2.0f);
    spmm_row_k<<<RGRID, 256, 0, stream>>>(rd1, csr, X5, X4, X6, 2.0f);

    epilogue_mfma_k<<<epgrid, 256, 0, stream>>>(xs, W, bias, out);
}

// Round 5
// 236.029 us; speedup vs baseline: 1.4500x; 1.4500x over previous
//
#include <hip/hip_runtime.h>

// Problem constants (from reference)
#define N_NODES 20000
#define BATCH   4
#define DIN     32
#define DOUT    64
#define MSTEPS  7            // M = MAX_STEP*S + 1
#define ROW     128          // DIN*BATCH, channels per node
#define NROW    896          // ROW*MSTEPS elements per node (all m packed), bf16
#define NROWU   448          // NROW in uints
#define PLN     656          // LDS plane stride (shorts): 16 rows * 40 + 16 pad
#define NT      79           // 256-node dst tiles per support (79*256 >= 20000)
#define KB2     (2 * NT)     // coarse buckets = 158
#define CHUNK   2048         // P2 edges per block
#define SLOT    12288        // staged slot per bucket (mean 8192, +45 sigma)
#define WSLOT   3584         // csr slot per 64-node window (mean 2048 + pad, +24 sigma)
#define RGRID   (N_NODES / 4)   // spmm blocks per stream (4 nodes/block)
#define PGRID   625             // ceil(2E / CHUNK) for E=640000
#define TGRID   1250            // N*16 threads / 256 (vectorized transpose)

typedef short  short8 __attribute__((ext_vector_type(8)));
typedef float  f32x4  __attribute__((ext_vector_type(4)));

__device__ __forceinline__ unsigned short f2bf(float f) {
    unsigned u = __float_as_uint(f);
    unsigned r = u + 0x7fff + ((u >> 16) & 1);   // RNE to bf16
    return (unsigned short)(r >> 16);
}
__device__ __forceinline__ float bf_lo(unsigned p) { return __uint_as_float(p << 16); }
__device__ __forceinline__ float bf_hi(unsigned p) { return __uint_as_float(p & 0xffff0000u); }

// slot-cursor init (must precede the fused partition kernel)
__global__ void init_k(int* __restrict__ cursor) {
    if (threadIdx.x < KB2) cursor[threadIdx.x] = threadIdx.x * SLOT;
}

// ---- Fused P2-partition + input-transpose (disjoint block ranges overlap) ----
// blocks [0,PGRID): LDS-staged partition of edges into coarse (s, dst>>8)
//   bucket slots; staged entry {src|bf16val<<16, dst}.
// blocks [PGRID, PGRID+TGRID): vectorized transpose into the m=0 slice with
//   row layout [m][b][d] (d fastest): xs[n*896 + b*32 + d] = bf16(in[b,n,d]).
//   Thread = (n, b, d-octet): 32B coalesced float read, 16B uint4 write.
__global__ void __launch_bounds__(256) p2t_k(const int* __restrict__ src,
                                             const int* __restrict__ dst,
                                             const float* __restrict__ vals,
                                             int* __restrict__ cursor,
                                             uint2* __restrict__ staged,
                                             const float* __restrict__ in,
                                             unsigned short* __restrict__ xs, int E) {
    __shared__ int lhist[KB2];
    __shared__ int lbase[KB2];
    __shared__ int gbase[KB2];
    __shared__ int sc[256];
    __shared__ uint2 buf[CHUNK];
    __shared__ unsigned short kk[CHUNK];
    int t = threadIdx.x;
    if (blockIdx.x >= PGRID) {
        // transpose branch: N*16 threads total
        int tid = (blockIdx.x - PGRID) * 256 + t;
        if (tid < N_NODES * 16) {
            int dq = tid & 3;             // d-octet
            int b  = (tid >> 2) & 3;
            int n  = tid >> 4;
            int d0 = dq * 8;
            const float* ip = in + ((size_t)b * N_NODES + n) * DIN + d0;
            float4 f0 = *(const float4*)ip;
            float4 f1 = *(const float4*)(ip + 4);
            uint4 o;
            o.x = (unsigned)f2bf(f0.x) | ((unsigned)f2bf(f0.y) << 16);
            o.y = (unsigned)f2bf(f0.z) | ((unsigned)f2bf(f0.w) << 16);
            o.z = (unsigned)f2bf(f1.x) | ((unsigned)f2bf(f1.y) << 16);
            o.w = (unsigned)f2bf(f1.z) | ((unsigned)f2bf(f1.w) << 16);
            *(uint4*)(xs + (size_t)n * NROW + b * 32 + d0) = o;
        }
        return;
    }
    int base = blockIdx.x * CHUNK;
    int nval = min(CHUNK, 2 * E - base);
    for (int i = t; i < KB2; i += 256) lhist[i] = 0;
    __syncthreads();
    int k[CHUNK / 256], pos[CHUNK / 256];
    uint2 pay[CHUNK / 256];
#pragma unroll
    for (int j = 0; j < CHUNK / 256; ++j) {
        int i = j * 256 + t;
        int e = base + i;
        if (i < nval) {
            int s = (e >= E) ? 1 : 0;
            int d = dst[e];
            pay[j] = make_uint2((unsigned)src[e] | ((unsigned)f2bf(vals[e]) << 16),
                                (unsigned)d);
            k[j] = s * NT + (d >> 8);
            pos[j] = atomicAdd(&lhist[k[j]], 1);
        } else k[j] = -1;
    }
    __syncthreads();
    int v = (t < KB2) ? lhist[t] : 0;
    sc[t] = v;
    __syncthreads();
    for (int off = 1; off < 256; off <<= 1) {
        int a = (t >= off) ? sc[t - off] : 0;
        __syncthreads();
        sc[t] += a;
        __syncthreads();
    }
    if (t < KB2) lbase[t] = sc[t] - v;
    __syncthreads();
    if (t < KB2 && lhist[t]) gbase[t] = atomicAdd(&cursor[t], lhist[t]);
#pragma unroll
    for (int j = 0; j < CHUNK / 256; ++j) {
        if (k[j] >= 0) {
            int slot = lbase[k[j]] + pos[j];
            buf[slot] = pay[j];
            kk[slot] = (unsigned short)k[j];
        }
    }
    __syncthreads();
#pragma unroll
    for (int j = 0; j < CHUNK / 256; ++j) {
        int i = j * 256 + t;
        if (i < nval) {
            int b = kk[i];
            staged[gbase[b] + (i - lbase[b])] = buf[i];
        }
    }
}

// P3: one block per 64-node window (4 windows per bucket, grid 4*KB2).
// Rows padded to x8 with {src=0,val=0}; writes row_desc {start, padded_cnt}.
__global__ void __launch_bounds__(256) p3_fine_k(const uint2* __restrict__ staged,
                                                 const int* __restrict__ cursor,
                                                 int2* __restrict__ row_desc,
                                                 unsigned* __restrict__ csr) {
    __shared__ int lhist[64];
    __shared__ int sc[64];
    __shared__ int lcur[64];
    int bb = blockIdx.x;
    int b = bb >> 2, sub = bb & 3;
    int s = b / NT, tile = b - s * NT;
    int w0loc = sub * 64;                    // window start within tile
    int seg0 = b * SLOT;
    int len = cursor[b] - seg0;
    int t = threadIdx.x;
    if (t < 64) lhist[t] = 0;
    __syncthreads();
    for (int i = t; i < len; i += 256) {
        int dl = (int)(staged[seg0 + i].y & 255) - w0loc;
        if (dl >= 0 && dl < 64) atomicAdd(&lhist[dl], 1);
    }
    __syncthreads();
    int cntr = (t < 64) ? lhist[t] : 0;
    int pl = (cntr + 7) & ~7;
    if (t < 64) sc[t] = pl;
    __syncthreads();
    for (int off = 1; off < 64; off <<= 1) {
        int a = (t < 64 && t >= off) ? sc[t - off] : 0;
        __syncthreads();
        if (t < 64) sc[t] += a;
        __syncthreads();
    }
    int wbase = bb * WSLOT;
    if (t < 64) {
        int excl = sc[t] - pl;
        lcur[t] = wbase + excl;
        int nd = tile * 256 + w0loc + t;
        if (nd < N_NODES) row_desc[s * N_NODES + nd] = make_int2(wbase + excl, pl);
    }
    __syncthreads();
    for (int i = t; i < len; i += 256) {
        uint2 u = staged[seg0 + i];
        int dl = (int)(u.y & 255) - w0loc;
        if (dl >= 0 && dl < 64) {
            int p = atomicAdd(&lcur[dl], 1);
            csr[p] = u.x;
        }
    }
    if (t < 64) {
        int excl = sc[t] - pl;
        for (int i = cntr; i < pl; ++i) csr[wbase + excl + i] = 0u;
    }
}

// ---- SpMM gather core (R1-verified): rows are multiples of 8, no tail ----
__device__ __forceinline__ void spmm_core(const int2* __restrict__ rdesc,
                                          const unsigned* __restrict__ csr,
                                          const unsigned* __restrict__ xb,
                                          const unsigned* __restrict__ xprevb,
                                          unsigned* __restrict__ yb,
                                          float alpha, int node, int lane) {
    int2 rd = rdesc[node];
    int start = rd.x, end = rd.x + rd.y;
    float l0 = 0.f, h0 = 0.f, l1 = 0.f, h1 = 0.f;
    float l2 = 0.f, h2 = 0.f, l3 = 0.f, h3 = 0.f;
    for (int e = start; e < end; e += 8) {
        unsigned c0 = csr[e],     c1 = csr[e + 1], c2 = csr[e + 2], c3 = csr[e + 3];
        unsigned c4 = csr[e + 4], c5 = csr[e + 5], c6 = csr[e + 6], c7 = csr[e + 7];
        unsigned p0 = xb[(size_t)(c0 & 0xffffu) * NROWU + lane];
        unsigned p1 = xb[(size_t)(c1 & 0xffffu) * NROWU + lane];
        unsigned p2 = xb[(size_t)(c2 & 0xffffu) * NROWU + lane];
        unsigned p3 = xb[(size_t)(c3 & 0xffffu) * NROWU + lane];
        unsigned p4 = xb[(size_t)(c4 & 0xffffu) * NROWU + lane];
        unsigned p5 = xb[(size_t)(c5 & 0xffffu) * NROWU + lane];
        unsigned p6 = xb[(size_t)(c6 & 0xffffu) * NROWU + lane];
        unsigned p7 = xb[(size_t)(c7 & 0xffffu) * NROWU + lane];
        float v0 = bf_hi(c0), v1 = bf_hi(c1), v2 = bf_hi(c2), v3 = bf_hi(c3);
        float v4 = bf_hi(c4), v5 = bf_hi(c5), v6 = bf_hi(c6), v7 = bf_hi(c7);
        l0 = fmaf(v0, bf_lo(p0), l0);  h0 = fmaf(v0, bf_hi(p0), h0);
        l1 = fmaf(v1, bf_lo(p1), l1);  h1 = fmaf(v1, bf_hi(p1), h1);
        l2 = fmaf(v2, bf_lo(p2), l2);  h2 = fmaf(v2, bf_hi(p2), h2);
        l3 = fmaf(v3, bf_lo(p3), l3);  h3 = fmaf(v3, bf_hi(p3), h3);
        l0 = fmaf(v4, bf_lo(p4), l0);  h0 = fmaf(v4, bf_hi(p4), h0);
        l1 = fmaf(v5, bf_lo(p5), l1);  h1 = fmaf(v5, bf_hi(p5), h1);
        l2 = fmaf(v6, bf_lo(p6), l2);  h2 = fmaf(v6, bf_hi(p6), h2);
        l3 = fmaf(v7, bf_lo(p7), l3);  h3 = fmaf(v7, bf_hi(p7), h3);
    }
    float r0 = alpha * ((l0 + l1) + (l2 + l3));
    float r1 = alpha * ((h0 + h1) + (h2 + h3));
    if (xprevb) {
        unsigned pp = xprevb[(size_t)node * NROWU + lane];
        r0 -= bf_lo(pp);
        r1 -= bf_hi(pp);
    }
    yb[(size_t)node * NROWU + lane] = (unsigned)f2bf(r0) | ((unsigned)f2bf(r1) << 16);
}

__global__ void __launch_bounds__(256) spmm_row_k(const int2* __restrict__ rdesc,
                                                  const unsigned* __restrict__ csr,
                                                  const unsigned short* __restrict__ x,
                                                  const unsigned short* __restrict__ xprev,
                                                  unsigned short* __restrict__ y, float alpha) {
    int node = __builtin_amdgcn_readfirstlane(blockIdx.x * 4 + (threadIdx.x >> 6));
    int lane = threadIdx.x & 63;
    spmm_core(rdesc, csr, (const unsigned*)x, (const unsigned*)xprev, (unsigned*)y,
              alpha, node, lane);
}

// dual dispatch: blocks [0,RGRID) A-stream, [RGRID,2*RGRID) B-stream, same input x.
// x3 = 2*A0*x2 - x1 ; x4 = A1*x2.
__global__ void __launch_bounds__(256) spmm_dual_k(const int2* __restrict__ rdA,
                                                   const int2* __restrict__ rdB,
                                                   const unsigned* __restrict__ csr,
                                                   const unsigned short* __restrict__ x,
                                                   const unsigned short* __restrict__ xprevA,
                                                   unsigned short* __restrict__ yA,
                                                   unsigned short* __restrict__ yB) {
    int bid = blockIdx.x;
    int second = (bid >= RGRID) ? 1 : 0;
    int node = __builtin_amdgcn_readfirstlane((bid - second * RGRID) * 4 + (threadIdx.x >> 6));
    int lane = threadIdx.x & 63;
    const int2* rd = second ? rdB : rdA;
    const unsigned* xprevb = second ? nullptr : (const unsigned*)xprevA;
    unsigned* yb = second ? (unsigned*)yB : (unsigned*)yA;
    float alpha = second ? 1.0f : 2.0f;
    spmm_core(rd, csr, (const unsigned*)x, xprevb, yb, alpha, node, lane);
}

// ---- MFMA epilogue: row layout [m][b][d] -> LDS stage is one ds_write_b128
// per uint4 (d-contiguous runs), replacing 8 ds_write_b16. MFMA mapping
// unchanged: A[k=d] read from plane (b*7+m) at col*40 + quad*8.
__global__ void __launch_bounds__(256) epilogue_mfma_k(const unsigned short* __restrict__ xs,
                                                       const float* __restrict__ W,
                                                       const float* __restrict__ bias,
                                                       float* __restrict__ out) {
    __shared__ unsigned short Alds[28 * PLN];   // 36736 B
    int tid = threadIdx.x;
    int lane = tid & 63, ot = tid >> 6;
    int col = lane & 15, quad = lane >> 4;
    int o = ot * 16 + col;

    short8 bfrag[MSTEPS];
#pragma unroll
    for (int m = 0; m < MSTEPS; ++m) {
        short8 bf;
#pragma unroll
        for (int j = 0; j < 8; ++j)
            bf[j] = (short)f2bf(W[o * 224 + (quad * 8 + j) * 7 + m]);
        bfrag[m] = bf;
    }
    float bo = bias[o];

    int n0 = blockIdx.x * 16;
    const uint4* src = (const uint4*)(xs + (size_t)n0 * NROW);   // 1792 uint4
#pragma unroll
    for (int it = 0; it < 7; ++it) {
        int idx = tid + it * 256;
        uint4 q = src[idx];
        int r   = idx / 112;             // node row 0..15
        int rem = idx - r * 112;         // uint4 within row: [m][b][dq]
        int m   = rem >> 4;
        int b   = (rem >> 2) & 3;
        int d0  = (rem & 3) * 8;
        *(uint4*)&Alds[(b * 7 + m) * PLN + r * 40 + d0] = q;
    }
    __syncthreads();

    f32x4 acc[BATCH];
#pragma unroll
    for (int b = 0; b < BATCH; ++b)
        acc[b] = (f32x4){bo, bo, bo, bo};

#pragma unroll
    for (int m = 0; m < MSTEPS; ++m) {
#pragma unroll
        for (int b = 0; b < BATCH; ++b) {
            short8 a = *(const short8*)&Alds[(b * 7 + m) * PLN + col * 40 + quad * 8];
            acc[b] = __builtin_amdgcn_mfma_f32_16x16x32_bf16(a, bfrag[m], acc[b], 0, 0, 0);
        }
    }

#pragma unroll
    for (int b = 0; b < BATCH; ++b) {
#pragma unroll
        for (int reg = 0; reg < 4; ++reg) {
            int n = n0 + quad * 4 + reg;
            out[((size_t)b * N_NODES + n) * DOUT + o] = acc[b][reg];
        }
    }
}

extern "C" void kernel_launch(void* const* d_in, const int* in_sizes, int n_in,
                              void* d_out, int out_size, void* d_ws, size_t ws_size,
                              hipStream_t stream) {
    const float* inputs    = (const float*)d_in[0];
    const float* edge_vals = (const float*)d_in[1];
    const float* W         = (const float*)d_in[2];
    const float* bias      = (const float*)d_in[3];
    const int*   edge_src  = (const int*)d_in[4];
    const int*   edge_dst  = (const int*)d_in[5];
    float* out = (float*)d_out;
    const int E = in_sizes[1] / 2;   // edges per support

    unsigned short* xs = (unsigned short*)d_ws;                    // 35.84 MB
    uint2* staged  = (uint2*)(xs + (size_t)N_NODES * NROW);        // KB2*SLOT*8 = 15.5 MB
    unsigned* csr  = (unsigned*)(staged + (size_t)KB2 * SLOT);     // 4*KB2*WSLOT*4 = 9.1 MB
    int* cursor    = (int*)(csr + (size_t)4 * KB2 * WSLOT);        // KB2
    int2* row_desc = (int2*)(cursor + KB2 + 2);                    // 2*N int2

    const int epgrid = N_NODES / 16;

    // ---- CSR build + transpose: init -> fused(partition || transpose) -> fine ----
    init_k<<<1, 256, 0, stream>>>(cursor);
    p2t_k<<<PGRID + TGRID, 256, 0, stream>>>(edge_src, edge_dst, edge_vals, cursor,
                                             staged, inputs, xs, E);
    p3_fine_k<<<4 * KB2, 256, 0, stream>>>(staged, cursor, row_desc, csr);

    const int2* rd0 = row_desc;
    const int2* rd1 = row_desc + N_NODES;

    // xs_m slice base = xs + m*128 (node stride NROW elements)
    unsigned short* X0 = xs + 0 * ROW;
    unsigned short* X1 = xs + 1 * ROW;
    unsigned short* X2 = xs + 2 * ROW;
    unsigned short* X3 = xs + 3 * ROW;
    unsigned short* X4 = xs + 4 * ROW;
    unsigned short* X5 = xs + 5 * ROW;
    unsigned short* X6 = xs + 6 * ROW;

    // support 0: xs1 = A0 x0 ; xs2 = 2 A0 xs1 - xs0
    spmm_row_k<<<RGRID, 256, 0, stream>>>(rd0, csr, X0, nullptr, X1, 1.0f);
    spmm_row_k<<<RGRID, 256, 0, stream>>>(rd0, csr, X1, X0,      X2, 2.0f);
    // xs3 = 2 A0 xs2 - xs1  ||  xs4 = A1 xs2   (independent; merged dispatch)
    spmm_dual_k<<<2 * RGRID, 256, 0, stream>>>(rd0, rd1, csr, X2, X1, X3, X4);
    // support 1 tail: xs5 = 2 A1 xs4 - xs2 ; xs6 = 2 A1 xs5 - xs4
    spmm_row_k<<<RGRID, 256, 0, stream>>>(rd1, csr, X4, X2, X5, 2.0f);
    spmm_row_k<<<RGRID, 256, 0, stream>>>(rd1, csr, X5, X4, X6, 2.0f);

    epilogue_mfma_k<<<epgrid, 256, 0, stream>>>(xs, W, bias, out);
}

// Round 6
// 227.897 us; speedup vs baseline: 1.5018x; 1.0357x over previous
//
#include <hip/hip_runtime.h>

// Problem constants (from reference)
#define N_NODES 20000
#define BATCH   4
#define DIN     32
#define DOUT    64
#define MSTEPS  7            // M = MAX_STEP*S + 1
#define ROW     128          // DIN*BATCH, channels per node
#define NROW    896          // ROW*MSTEPS elements per node (all m packed), bf16
#define NROWU   448          // NROW in uints
#define PLN     656          // LDS plane stride (shorts): 16 rows * 40 + 16 pad
#define NT      79           // 256-node dst tiles per support (79*256 >= 20000)
#define KB2     (2 * NT)     // coarse buckets = 158
#define CHUNK   2048         // P2 edges per block
#define SLOT    12288        // staged slot per bucket (mean 8192, +45 sigma)
#define WSLOT   3584         // csr slot per 64-node window (pad16 worst-case 3144)
#define RGRID   (N_NODES / 4)   // spmm blocks per stream (4 nodes/block)
#define PGRID   625             // ceil(2E / CHUNK) for E=640000
#define TGRID   1250            // N*16 threads / 256 (vectorized transpose)

typedef short  short8 __attribute__((ext_vector_type(8)));
typedef float  f32x4  __attribute__((ext_vector_type(4)));

__device__ __forceinline__ unsigned short f2bf(float f) {
    unsigned u = __float_as_uint(f);
    unsigned r = u + 0x7fff + ((u >> 16) & 1);   // RNE to bf16
    return (unsigned short)(r >> 16);
}
__device__ __forceinline__ float bf_lo(unsigned p) { return __uint_as_float(p << 16); }
__device__ __forceinline__ float bf_hi(unsigned p) { return __uint_as_float(p & 0xffff0000u); }

// slot-cursor init (must precede the fused partition kernel)
__global__ void init_k(int* __restrict__ cursor) {
    if (threadIdx.x < KB2) cursor[threadIdx.x] = threadIdx.x * SLOT;
}

// ---- Fused P2-partition + input-transpose (disjoint block ranges overlap) ----
// blocks [0,PGRID): LDS-staged partition of edges into coarse (s, dst>>8)
//   bucket slots; staged entry {src|bf16val<<16, dst}.
// blocks [PGRID, PGRID+TGRID): vectorized transpose into the m=0 slice with
//   row layout [m][b][d] (d fastest): xs[n*896 + b*32 + d] = bf16(in[b,n,d]).
__global__ void __launch_bounds__(256) p2t_k(const int* __restrict__ src,
                                             const int* __restrict__ dst,
                                             const float* __restrict__ vals,
                                             int* __restrict__ cursor,
                                             uint2* __restrict__ staged,
                                             const float* __restrict__ in,
                                             unsigned short* __restrict__ xs, int E) {
    __shared__ int lhist[KB2];
    __shared__ int lbase[KB2];
    __shared__ int gbase[KB2];
    __shared__ int sc[256];
    __shared__ uint2 buf[CHUNK];
    __shared__ unsigned short kk[CHUNK];
    int t = threadIdx.x;
    if (blockIdx.x >= PGRID) {
        // transpose branch: N*16 threads total
        int tid = (blockIdx.x - PGRID) * 256 + t;
        if (tid < N_NODES * 16) {
            int dq = tid & 3;             // d-octet
            int b  = (tid >> 2) & 3;
            int n  = tid >> 4;
            int d0 = dq * 8;
            const float* ip = in + ((size_t)b * N_NODES + n) * DIN + d0;
            float4 f0 = *(const float4*)ip;
            float4 f1 = *(const float4*)(ip + 4);
            uint4 o;
            o.x = (unsigned)f2bf(f0.x) | ((unsigned)f2bf(f0.y) << 16);
            o.y = (unsigned)f2bf(f0.z) | ((unsigned)f2bf(f0.w) << 16);
            o.z = (unsigned)f2bf(f1.x) | ((unsigned)f2bf(f1.y) << 16);
            o.w = (unsigned)f2bf(f1.z) | ((unsigned)f2bf(f1.w) << 16);
            *(uint4*)(xs + (size_t)n * NROW + b * 32 + d0) = o;
        }
        return;
    }
    int base = blockIdx.x * CHUNK;
    int nval = min(CHUNK, 2 * E - base);
    for (int i = t; i < KB2; i += 256) lhist[i] = 0;
    __syncthreads();
    int k[CHUNK / 256], pos[CHUNK / 256];
    uint2 pay[CHUNK / 256];
#pragma unroll
    for (int j = 0; j < CHUNK / 256; ++j) {
        int i = j * 256 + t;
        int e = base + i;
        if (i < nval) {
            int s = (e >= E) ? 1 : 0;
            int d = dst[e];
            pay[j] = make_uint2((unsigned)src[e] | ((unsigned)f2bf(vals[e]) << 16),
                                (unsigned)d);
            k[j] = s * NT + (d >> 8);
            pos[j] = atomicAdd(&lhist[k[j]], 1);
        } else k[j] = -1;
    }
    __syncthreads();
    int v = (t < KB2) ? lhist[t] : 0;
    sc[t] = v;
    __syncthreads();
    for (int off = 1; off < 256; off <<= 1) {
        int a = (t >= off) ? sc[t - off] : 0;
        __syncthreads();
        sc[t] += a;
        __syncthreads();
    }
    if (t < KB2) lbase[t] = sc[t] - v;
    __syncthreads();
    if (t < KB2 && lhist[t]) gbase[t] = atomicAdd(&cursor[t], lhist[t]);
#pragma unroll
    for (int j = 0; j < CHUNK / 256; ++j) {
        if (k[j] >= 0) {
            int slot = lbase[k[j]] + pos[j];
            buf[slot] = pay[j];
            kk[slot] = (unsigned short)k[j];
        }
    }
    __syncthreads();
#pragma unroll
    for (int j = 0; j < CHUNK / 256; ++j) {
        int i = j * 256 + t;
        if (i < nval) {
            int b = kk[i];
            staged[gbase[b] + (i - lbase[b])] = buf[i];
        }
    }
}

// P3: one block per 64-node window (4 windows per bucket, grid 4*KB2).
// Rows padded to x16 with {src=0,val=0}; writes row_desc {start, padded_cnt}.
__global__ void __launch_bounds__(256) p3_fine_k(const uint2* __restrict__ staged,
                                                 const int* __restrict__ cursor,
                                                 int2* __restrict__ row_desc,
                                                 unsigned* __restrict__ csr) {
    __shared__ int lhist[64];
    __shared__ int sc[64];
    __shared__ int lcur[64];
    int bb = blockIdx.x;
    int b = bb >> 2, sub = bb & 3;
    int s = b / NT, tile = b - s * NT;
    int w0loc = sub * 64;                    // window start within tile
    int seg0 = b * SLOT;
    int len = cursor[b] - seg0;
    int t = threadIdx.x;
    if (t < 64) lhist[t] = 0;
    __syncthreads();
    for (int i = t; i < len; i += 256) {
        int dl = (int)(staged[seg0 + i].y & 255) - w0loc;
        if (dl >= 0 && dl < 64) atomicAdd(&lhist[dl], 1);
    }
    __syncthreads();
    int cntr = (t < 64) ? lhist[t] : 0;
    int pl = (cntr + 15) & ~15;              // pad to x16 for the pipelined gather core
    if (t < 64) sc[t] = pl;
    __syncthreads();
    for (int off = 1; off < 64; off <<= 1) {
        int a = (t < 64 && t >= off) ? sc[t - off] : 0;
        __syncthreads();
        if (t < 64) sc[t] += a;
        __syncthreads();
    }
    int wbase = bb * WSLOT;
    if (t < 64) {
        int excl = sc[t] - pl;
        lcur[t] = wbase + excl;
        int nd = tile * 256 + w0loc + t;
        if (nd < N_NODES) row_desc[s * N_NODES + nd] = make_int2(wbase + excl, pl);
    }
    __syncthreads();
    for (int i = t; i < len; i += 256) {
        uint2 u = staged[seg0 + i];
        int dl = (int)(u.y & 255) - w0loc;
        if (dl >= 0 && dl < 64) {
            int p = atomicAdd(&lcur[dl], 1);
            csr[p] = u.x;
        }
    }
    if (t < 64) {
        int excl = sc[t] - pl;
        for (int i = cntr; i < pl; ++i) csr[wbase + excl + i] = 0u;
    }
}

// ---- SpMM gather core, 16-wide 2-deep software pipeline ----
// Rows are multiples of 16 (pad {src=0,val=0}). Per 16-edge chunk: 4 scalar
// dwordx4 csr loads + 16 gathers issued as a batch; the pipeline overlaps
// chunk k+1's gathers with chunk k's FMAs so the L2/L3 latency is exposed
// ~once per row instead of once per 8 edges (the R5 core's limiter:
// VGPR=16 => vmcnt(0) each 8 edges).
__device__ __forceinline__ void issue16(const unsigned* __restrict__ csr, int e,
                                        const unsigned* __restrict__ xb, int lane,
                                        unsigned c[16], unsigned p[16]) {
    uint4 q0 = *(const uint4*)(csr + e);
    uint4 q1 = *(const uint4*)(csr + e + 4);
    uint4 q2 = *(const uint4*)(csr + e + 8);
    uint4 q3 = *(const uint4*)(csr + e + 12);
    c[0]=q0.x;  c[1]=q0.y;  c[2]=q0.z;  c[3]=q0.w;
    c[4]=q1.x;  c[5]=q1.y;  c[6]=q1.z;  c[7]=q1.w;
    c[8]=q2.x;  c[9]=q2.y;  c[10]=q2.z; c[11]=q2.w;
    c[12]=q3.x; c[13]=q3.y; c[14]=q3.z; c[15]=q3.w;
#pragma unroll
    for (int j = 0; j < 16; ++j)
        p[j] = xb[(size_t)(c[j] & 0xffffu) * NROWU + lane];
}

__device__ __forceinline__ void fmac16(const unsigned c[16], const unsigned p[16],
                                       float acc[8]) {
#pragma unroll
    for (int j = 0; j < 16; ++j) {
        float v = bf_hi(c[j]);
        acc[j & 3]       = fmaf(v, bf_lo(p[j]), acc[j & 3]);
        acc[4 + (j & 3)] = fmaf(v, bf_hi(p[j]), acc[4 + (j & 3)]);
    }
}

__device__ __forceinline__ void spmm_core(const int2* __restrict__ rdesc,
                                          const unsigned* __restrict__ csr,
                                          const unsigned* __restrict__ xb,
                                          const unsigned* __restrict__ xprevb,
                                          unsigned* __restrict__ yb,
                                          float alpha, int node, int lane) {
    int2 rd = rdesc[node];
    int start = rd.x, len = rd.y;
    float acc[8];
#pragma unroll
    for (int j = 0; j < 8; ++j) acc[j] = 0.f;
    if (len) {
        unsigned cA[16], pA[16], cB[16], pB[16];
        int n16 = len >> 4;
        issue16(csr, start, xb, lane, cA, pA);
        int k = 1;
        for (; k + 1 < n16; k += 2) {
            issue16(csr, start + k * 16, xb, lane, cB, pB);
            fmac16(cA, pA, acc);
            issue16(csr, start + (k + 1) * 16, xb, lane, cA, pA);
            fmac16(cB, pB, acc);
        }
        if (k < n16) {
            issue16(csr, start + k * 16, xb, lane, cB, pB);
            fmac16(cA, pA, acc);
            fmac16(cB, pB, acc);
        } else {
            fmac16(cA, pA, acc);
        }
    }
    float r0 = alpha * ((acc[0] + acc[1]) + (acc[2] + acc[3]));
    float r1 = alpha * ((acc[4] + acc[5]) + (acc[6] + acc[7]));
    if (xprevb) {
        unsigned pp = xprevb[(size_t)node * NROWU + lane];
        r0 -= bf_lo(pp);
        r1 -= bf_hi(pp);
    }
    yb[(size_t)node * NROWU + lane] = (unsigned)f2bf(r0) | ((unsigned)f2bf(r1) << 16);
}

__global__ void __launch_bounds__(256) spmm_row_k(const int2* __restrict__ rdesc,
                                                  const unsigned* __restrict__ csr,
                                                  const unsigned short* __restrict__ x,
                                                  const unsigned short* __restrict__ xprev,
                                                  unsigned short* __restrict__ y, float alpha) {
    int node = __builtin_amdgcn_readfirstlane(blockIdx.x * 4 + (threadIdx.x >> 6));
    int lane = threadIdx.x & 63;
    spmm_core(rdesc, csr, (const unsigned*)x, (const unsigned*)xprev, (unsigned*)y,
              alpha, node, lane);
}

// dual dispatch: blocks [0,RGRID) A-stream, [RGRID,2*RGRID) B-stream, same input x.
// x3 = 2*A0*x2 - x1 ; x4 = A1*x2.
__global__ void __launch_bounds__(256) spmm_dual_k(const int2* __restrict__ rdA,
                                                   const int2* __restrict__ rdB,
                                                   const unsigned* __restrict__ csr,
                                                   const unsigned short* __restrict__ x,
                                                   const unsigned short* __restrict__ xprevA,
                                                   unsigned short* __restrict__ yA,
                                                   unsigned short* __restrict__ yB) {
    int bid = blockIdx.x;
    int second = (bid >= RGRID) ? 1 : 0;
    int node = __builtin_amdgcn_readfirstlane((bid - second * RGRID) * 4 + (threadIdx.x >> 6));
    int lane = threadIdx.x & 63;
    const int2* rd = second ? rdB : rdA;
    const unsigned* xprevb = second ? nullptr : (const unsigned*)xprevA;
    unsigned* yb = second ? (unsigned*)yB : (unsigned*)yA;
    float alpha = second ? 1.0f : 2.0f;
    spmm_core(rd, csr, (const unsigned*)x, xprevb, yb, alpha, node, lane);
}

// ---- MFMA epilogue: row layout [m][b][d] -> LDS stage is one ds_write_b128
// per uint4 (d-contiguous runs). MFMA mapping unchanged.
__global__ void __launch_bounds__(256) epilogue_mfma_k(const unsigned short* __restrict__ xs,
                                                       const float* __restrict__ W,
                                                       const float* __restrict__ bias,
                                                       float* __restrict__ out) {
    __shared__ unsigned short Alds[28 * PLN];   // 36736 B
    int tid = threadIdx.x;
    int lane = tid & 63, ot = tid >> 6;
    int col = lane & 15, quad = lane >> 4;
    int o = ot * 16 + col;

    short8 bfrag[MSTEPS];
#pragma unroll
    for (int m = 0; m < MSTEPS; ++m) {
        short8 bf;
#pragma unroll
        for (int j = 0; j < 8; ++j)
            bf[j] = (short)f2bf(W[o * 224 + (quad * 8 + j) * 7 + m]);
        bfrag[m] = bf;
    }
    float bo = bias[o];

    int n0 = blockIdx.x * 16;
    const uint4* src = (const uint4*)(xs + (size_t)n0 * NROW);   // 1792 uint4
#pragma unroll
    for (int it = 0; it < 7; ++it) {
        int idx = tid + it * 256;
        uint4 q = src[idx];
        int r   = idx / 112;             // node row 0..15
        int rem = idx - r * 112;         // uint4 within row: [m][b][dq]
        int m   = rem >> 4;
        int b   = (rem >> 2) & 3;
        int d0  = (rem & 3) * 8;
        *(uint4*)&Alds[(b * 7 + m) * PLN + r * 40 + d0] = q;
    }
    __syncthreads();

    f32x4 acc[BATCH];
#pragma unroll
    for (int b = 0; b < BATCH; ++b)
        acc[b] = (f32x4){bo, bo, bo, bo};

#pragma unroll
    for (int m = 0; m < MSTEPS; ++m) {
#pragma unroll
        for (int b = 0; b < BATCH; ++b) {
            short8 a = *(const short8*)&Alds[(b * 7 + m) * PLN + col * 40 + quad * 8];
            acc[b] = __builtin_amdgcn_mfma_f32_16x16x32_bf16(a, bfrag[m], acc[b], 0, 0, 0);
        }
    }

#pragma unroll
    for (int b = 0; b < BATCH; ++b) {
#pragma unroll
        for (int reg = 0; reg < 4; ++reg) {
            int n = n0 + quad * 4 + reg;
            out[((size_t)b * N_NODES + n) * DOUT + o] = acc[b][reg];
        }
    }
}

extern "C" void kernel_launch(void* const* d_in, const int* in_sizes, int n_in,
                              void* d_out, int out_size, void* d_ws, size_t ws_size,
                              hipStream_t stream) {
    const float* inputs    = (const float*)d_in[0];
    const float* edge_vals = (const float*)d_in[1];
    const float* W         = (const float*)d_in[2];
    const float* bias      = (const float*)d_in[3];
    const int*   edge_src  = (const int*)d_in[4];
    const int*   edge_dst  = (const int*)d_in[5];
    float* out = (float*)d_out;
    const int E = in_sizes[1] / 2;   // edges per support

    unsigned short* xs = (unsigned short*)d_ws;                    // 35.84 MB
    uint2* staged  = (uint2*)(xs + (size_t)N_NODES * NROW);        // KB2*SLOT*8 = 15.5 MB
    unsigned* csr  = (unsigned*)(staged + (size_t)KB2 * SLOT);     // 4*KB2*WSLOT*4 = 9.1 MB
    int* cursor    = (int*)(csr + (size_t)4 * KB2 * WSLOT);        // KB2
    int2* row_desc = (int2*)(cursor + KB2 + 2);                    // 2*N int2

    const int epgrid = N_NODES / 16;

    // ---- CSR build + transpose: init -> fused(partition || transpose) -> fine ----
    init_k<<<1, 256, 0, stream>>>(cursor);
    p2t_k<<<PGRID + TGRID, 256, 0, stream>>>(edge_src, edge_dst, edge_vals, cursor,
                                             staged, inputs, xs, E);
    p3_fine_k<<<4 * KB2, 256, 0, stream>>>(staged, cursor, row_desc, csr);

    const int2* rd0 = row_desc;
    const int2* rd1 = row_desc + N_NODES;

    // xs_m slice base = xs + m*128 (node stride NROW elements)
    unsigned short* X0 = xs + 0 * ROW;
    unsigned short* X1 = xs + 1 * ROW;
    unsigned short* X2 = xs + 2 * ROW;
    unsigned short* X3 = xs + 3 * ROW;
    unsigned short* X4 = xs + 4 * ROW;
    unsigned short* X5 = xs + 5 * ROW;
    unsigned short* X6 = xs + 6 * ROW;

    // support 0: xs1 = A0 x0 ; xs2 = 2 A0 xs1 - xs0
    spmm_row_k<<<RGRID, 256, 0, stream>>>(rd0, csr, X0, nullptr, X1, 1.0f);
    spmm_row_k<<<RGRID, 256, 0, stream>>>(rd0, csr, X1, X0,      X2, 2.0f);
    // xs3 = 2 A0 xs2 - xs1  ||  xs4 = A1 xs2   (independent; merged dispatch)
    spmm_dual_k<<<2 * RGRID, 256, 0, stream>>>(rd0, rd1, csr, X2, X1, X3, X4);
    // support 1 tail: xs5 = 2 A1 xs4 - xs2 ; xs6 = 2 A1 xs5 - xs4
    spmm_row_k<<<RGRID, 256, 0, stream>>>(rd1, csr, X4, X2, X5, 2.0f);
    spmm_row_k<<<RGRID, 256, 0, stream>>>(rd1, csr, X5, X4, X6, 2.0f);

    epilogue_mfma_k<<<epgrid, 256, 0, stream>>>(xs, W, bias, out);
}